// Round 8
// baseline (187.692 us; speedup 1.0000x reference)
//
#include <hip/hip_runtime.h>
#include <math.h>

// ClownSelector R8: R7 tile + latency pipelining + 2x occupancy.
//
// R7 post-mortem: dots was latency-bound (VALUBusy 24%, VGPR=48 -> compiler
// built no load pipeline; ~200cyc L2 proto waits per k-step + ~600cyc HBM
// x-stage waits per chunk, only 2 waves/SIMD). R8 keeps the 32tok x 64exp
// wave tile (4x8 thread tile, 32 acc) and adds:
//  1. proto register rotation depth 4: prefetch k+4's two quads while
//     fmac'ing k (256 VALU cyc of cover >> L2 latency)
//  2. double-buffered wave-private x staging: global-load chunk c+1 before
//     chunk c's k-loop, ds_write after it (DS in-order per wave -> still no
//     barriers in the K-loop)
//  3. 8 waves/block (512 thr), k-slice 128/wave, __launch_bounds__(512,4):
//     16 waves/CU = 4/SIMD, LDS 72.7KB -> 2 blocks/CU
// Reduction: 3-round LDS tree over 8 partials; fused L2-norm; K0/K2 are
// R7-verified and unchanged.

#define BB 8
#define SS 2048
#define DD 1024
#define EE 64
#define EPSV 1e-8f

#define NW 8      // waves per block
#define KSL 128   // k-slice per wave
#define NCHK 8    // chunks per wave (16 k each)

#define FMA4(A, s, P) \
  A.x += (s) * (P).x; A.y += (s) * (P).y; A.z += (s) * (P).z; A.w += (s) * (P).w;

#define SUMSQ4(v) ((v).x * (v).x + (v).y * (v).y + (v).z * (v).z + (v).w * (v).w)

// ---- K0: proto[e][d] -> ptt[d][e] -----------------------------------------
__global__ __launch_bounds__(256) void repack_proto(
    const float* __restrict__ proto, float* __restrict__ ptt) {
  const int gid = blockIdx.x * 256 + threadIdx.x;  // 0..65535
  const int d = gid >> 6;
  const int e = gid & 63;
  ptt[gid] = proto[(size_t)e * DD + d];
}

// ---- K1: normalized per-row dots ------------------------------------------
__global__ __launch_bounds__(512, 4) void router_dots(
    const float* __restrict__ x, const float* __restrict__ ptt,
    float* __restrict__ dots) {
  __shared__ float xt[NW][2][16][36];  // double-buffered per-wave x chunk
  __shared__ float B[4][32][68];       // reduction buffers
  __shared__ float nq[NW][32];         // per-wave per-token sumsq partials

  const int lane = threadIdx.x & 63;
  const int w    = __builtin_amdgcn_readfirstlane(threadIdx.x >> 6);  // 0..7
  const int b    = blockIdx.x >> 6;          // 64 blocks per batch
  const int s0   = (blockIdx.x & 63) * 32;   // 32 tokens per block

  const int toks = lane & 31;  // staging: token
  const int kh   = lane >> 5;  // staging: k-half (8 floats)
  const int eg   = lane & 7;   // tile: expert group (8 e)
  const int tg   = lane >> 3;  // tile: token group (4 t)

  const float* xb = x + ((size_t)b * SS + s0) * DD;
  const int kbase = w * KSL;

  float4 acc0[4], acc1[4];
#pragma unroll
  for (int i = 0; i < 4; ++i) {
    acc0[i] = make_float4(0.f, 0.f, 0.f, 0.f);
    acc1[i] = make_float4(0.f, 0.f, 0.f, 0.f);
  }
  float q = 0.0f;

  // ---- preload chunk 0 into buf 0 ----
  {
    const float* xs = xb + (size_t)toks * DD + kbase + kh * 8;
    const float4 va = *(const float4*)(xs);
    const float4 vb = *(const float4*)(xs + 4);
    q += SUMSQ4(va) + SUMSQ4(vb);
    float* dstc = &xt[w][0][0][toks];
    dstc[(kh * 8 + 0) * 36] = va.x;
    dstc[(kh * 8 + 1) * 36] = va.y;
    dstc[(kh * 8 + 2) * 36] = va.z;
    dstc[(kh * 8 + 3) * 36] = va.w;
    dstc[(kh * 8 + 4) * 36] = vb.x;
    dstc[(kh * 8 + 5) * 36] = vb.y;
    dstc[(kh * 8 + 6) * 36] = vb.z;
    dstc[(kh * 8 + 7) * 36] = vb.w;
  }

  // ---- proto rotation preload: k = kbase..kbase+3 ----
  float4 pp0[4], pp1[4];
#pragma unroll
  for (int r = 0; r < 4; ++r) {
    const float* pr = ptt + (size_t)(kbase + r) * EE + eg * 8;
    pp0[r] = *(const float4*)(pr);
    pp1[r] = *(const float4*)(pr + 4);
  }

  for (int c = 0; c < NCHK; ++c) {
    const int cur = c & 1;
    // ---- prefetch next chunk's x (consumed after the k-loop) ----
    float4 na, nb;
    if (c + 1 < NCHK) {
      const float* xs = xb + (size_t)toks * DD + kbase + (c + 1) * 16 + kh * 8;
      na = *(const float4*)(xs);
      nb = *(const float4*)(xs + 4);
    }
    // ---- 16 k-steps: ds_read x-frag + rotated proto + 32 fmac ----
#pragma unroll
    for (int kk = 0; kk < 16; ++kk) {
      const int slot = kk & 3;
      const float4 xf = *(const float4*)(&xt[w][cur][kk][tg * 4]);
      const float4 p0 = pp0[slot];
      const float4 p1 = pp1[slot];
      // prefetch k+4 into this slot (wave-uniform row index, clamped tail)
      int kpre = kbase + c * 16 + kk + 4;
      if (kpre > kbase + KSL - 1) kpre = kbase + KSL - 1;
      const float* pr = ptt + (size_t)kpre * EE + eg * 8;
      pp0[slot] = *(const float4*)(pr);
      pp1[slot] = *(const float4*)(pr + 4);
      FMA4(acc0[0], xf.x, p0) FMA4(acc1[0], xf.x, p1)
      FMA4(acc0[1], xf.y, p0) FMA4(acc1[1], xf.y, p1)
      FMA4(acc0[2], xf.z, p0) FMA4(acc1[2], xf.z, p1)
      FMA4(acc0[3], xf.w, p0) FMA4(acc1[3], xf.w, p1)
    }
    // ---- stage prefetched chunk into the other buffer ----
    if (c + 1 < NCHK) {
      q += SUMSQ4(na) + SUMSQ4(nb);
      float* dstc = &xt[w][cur ^ 1][0][toks];
      dstc[(kh * 8 + 0) * 36] = na.x;
      dstc[(kh * 8 + 1) * 36] = na.y;
      dstc[(kh * 8 + 2) * 36] = na.z;
      dstc[(kh * 8 + 3) * 36] = na.w;
      dstc[(kh * 8 + 4) * 36] = nb.x;
      dstc[(kh * 8 + 5) * 36] = nb.y;
      dstc[(kh * 8 + 6) * 36] = nb.z;
      dstc[(kh * 8 + 7) * 36] = nb.w;
    }
  }

  // sumsq: combine the two k-halves of each token; kh==0 lanes publish
  q += __shfl_xor(q, 32);
  if (kh == 0) nq[w][toks] = q;

#define WRB(R)                                                  \
  { _Pragma("unroll") for (int i = 0; i < 4; ++i) {             \
      *(float4*)(&(R)[tg * 4 + i][eg * 8])     = acc0[i];       \
      *(float4*)(&(R)[tg * 4 + i][eg * 8 + 4]) = acc1[i]; } }
#define ADDB(R)                                                 \
  { _Pragma("unroll") for (int i = 0; i < 4; ++i) {             \
      const float4 t0 = *(const float4*)(&(R)[tg * 4 + i][eg * 8]);     \
      const float4 t1 = *(const float4*)(&(R)[tg * 4 + i][eg * 8 + 4]); \
      acc0[i].x += t0.x; acc0[i].y += t0.y;                     \
      acc0[i].z += t0.z; acc0[i].w += t0.w;                     \
      acc1[i].x += t1.x; acc1[i].y += t1.y;                     \
      acc1[i].z += t1.z; acc1[i].w += t1.w; } }

  // deterministic 3-round tree over 8 partials
  __syncthreads();
  if (w & 1) WRB(B[w >> 1])                 // 1->B0 3->B1 5->B2 7->B3
  __syncthreads();
  if (!(w & 1)) ADDB(B[w >> 1])             // 0+=B0 2+=B1 4+=B2 6+=B3
  __syncthreads();
  if (w == 2) WRB(B[0])
  if (w == 6) WRB(B[1])
  __syncthreads();
  if (w == 0) ADDB(B[0])
  if (w == 4) ADDB(B[1])
  __syncthreads();
  if (w == 4) WRB(B[0])
  __syncthreads();
  if (w == 0) {
    ADDB(B[0])
#pragma unroll
    for (int i = 0; i < 4; ++i) {
      const int row = tg * 4 + i;
      float qs = 0.0f;
#pragma unroll
      for (int wv = 0; wv < NW; ++wv) qs += nq[wv][row];
      const float inv = 1.0f / fmaxf(sqrtf(qs), EPSV);
      float4 o0, o1;
      o0.x = acc0[i].x * inv; o0.y = acc0[i].y * inv;
      o0.z = acc0[i].z * inv; o0.w = acc0[i].w * inv;
      o1.x = acc1[i].x * inv; o1.y = acc1[i].y * inv;
      o1.z = acc1[i].z * inv; o1.w = acc1[i].w * inv;
      float* dp = dots + ((size_t)b * SS + s0 + row) * EE + eg * 8;
      *(float4*)(dp)     = o0;
      *(float4*)(dp + 4) = o1;
    }
  }
}

// ---- K2: window-3 + top-2 + renorm softmax (array-free, R7-verified) -------
#define T2UP(s, ei)                                            \
  if ((s) > v1) { v2 = v1; i2 = i1; v1 = (s); i1 = (ei); }     \
  else if ((s) > v2) { v2 = (s); i2 = (ei); }

__global__ __launch_bounds__(256) void router_top2(
    const float* __restrict__ dots, float* __restrict__ out) {
  const int gtid = blockIdx.x * 256 + threadIdx.x;  // 0..32767
  const int tok  = gtid >> 1;          // global token
  const int h    = gtid & 1;           // expert half (32 each)
  const int b    = tok >> 11;
  const int sl   = tok & (SS - 1);
  const int r0   = (sl >= 2) ? sl - 2 : 0;   // causal pad: replicate token 0
  const int r1   = (sl >= 1) ? sl - 1 : 0;

  const float* d0 = dots + ((size_t)b * SS + r0) * EE + h * 32;
  const float* d1 = dots + ((size_t)b * SS + r1) * EE + h * 32;
  const float* d2 = dots + ((size_t)b * SS + sl) * EE + h * 32;

  float v1 = -INFINITY, v2 = -INFINITY;
  int i1 = 0, i2 = 0;
#pragma unroll
  for (int qd = 0; qd < 8; ++qd) {
    const float4 a = *(const float4*)(d0 + qd * 4);
    const float4 c = *(const float4*)(d1 + qd * 4);
    const float4 e = *(const float4*)(d2 + qd * 4);
    const int e0 = h * 32 + qd * 4;
    float s;
    s = a.x + c.x + e.x; T2UP(s, e0 + 0)
    s = a.y + c.y + e.y; T2UP(s, e0 + 1)
    s = a.z + c.z + e.z; T2UP(s, e0 + 2)
    s = a.w + c.w + e.w; T2UP(s, e0 + 3)
  }

  {  // merge the two halves (partner lane = lane^1); tie -> lower index
    const float ov1 = __shfl_xor(v1, 1);
    const int   oi1 = __shfl_xor(i1, 1);
    const float ov2 = __shfl_xor(v2, 1);
    const int   oi2 = __shfl_xor(i2, 1);
    const bool o_beats = (ov1 > v1) || (ov1 == v1 && oi1 < i1);
    if (o_beats) {
      const bool v1_beats_o2 = (v1 > ov2) || (v1 == ov2 && i1 < oi2);
      v2 = v1_beats_o2 ? v1 : ov2;
      i2 = v1_beats_o2 ? i1 : oi2;
      v1 = ov1;
      i1 = oi1;
    } else {
      const bool o1_beats_v2 = (ov1 > v2) || (ov1 == v2 && oi1 < i2);
      if (o1_beats_v2) { v2 = ov1; i2 = oi1; }
    }
  }

  if (h == 0) {
    const float ex = expf((v2 - v1) * (1.0f / 3.0f));  // <= 1
    const float w1 = 1.0f / (1.0f + ex);
    const size_t o = (size_t)tok * 2;
    *(float2*)(out + o) = make_float2((float)i1, (float)i2);
    *(float2*)(out + (size_t)BB * SS * 2 + o) = make_float2(w1, ex * w1);
  }
}

extern "C" void kernel_launch(void* const* d_in, const int* in_sizes, int n_in,
                              void* d_out, int out_size, void* d_ws, size_t ws_size,
                              hipStream_t stream) {
  const float* x     = (const float*)d_in[0];
  const float* proto = (const float*)d_in[1];
  // d_in[2] = attn_mask: unused by the reference output path.
  float* out  = (float*)d_out;
  float* ptt  = (float*)d_ws;                          // 256 KiB ptt[d][e]
  float* dots = (float*)((char*)d_ws + (512 << 10));   // 4 MiB normalized dots

  repack_proto<<<dim3(256), dim3(256), 0, stream>>>(proto, ptt);
  router_dots<<<dim3(512), dim3(512), 0, stream>>>(x, ptt, dots);
  router_top2<<<dim3(128), dim3(256), 0, stream>>>(dots, out);
}

// Round 9
// 133.296 us; speedup vs baseline: 1.4081x; 1.4081x over previous
//
#include <hip/hip_runtime.h>
#include <math.h>

// ClownSelector R9: R7's proven tile + latency pipelining, loose reg bound.
//
// R8 post-mortem: __launch_bounds__(512,4) capped VGPR at 64 < the ~110-reg
// working set -> accumulator spills to scratch (WRITE_SIZE 4->124 MB, the
// smoking gun). R9 returns to R7's exact structure (passed, 62us, VGPR 48,
// launch_bounds(256,2) -> cap 256) and adds only:
//  1. proto register rotation depth 4 (+32 VGPR): prefetch k+4's two quads
//     while fmac'ing k; rotation is continuous across chunk boundaries
//     (k-slice is contiguous), clamped at the slice tail only.
//  2. x-chunk register double-buffer (+8 VGPR): global-load chunk c+1 before
//     chunk c's k-loop, ds_write after it. Wave-private LDS, DS in-order ->
//     still ZERO barriers in the K-loop.
// Everything else (tile, reduction tree, fused norm, K0, K2, epilogue math)
// is R7-verified and unchanged.

#define BB 8
#define SS 2048
#define DD 1024
#define EE 64
#define EPSV 1e-8f

#define FMA4(A, s, P) \
  A.x += (s) * (P).x; A.y += (s) * (P).y; A.z += (s) * (P).z; A.w += (s) * (P).w;

#define SUMSQ4(v) ((v).x * (v).x + (v).y * (v).y + (v).z * (v).z + (v).w * (v).w)

// ---- K0: proto[e][d] -> ptt[d][e] -----------------------------------------
__global__ __launch_bounds__(256) void repack_proto(
    const float* __restrict__ proto, float* __restrict__ ptt) {
  const int gid = blockIdx.x * 256 + threadIdx.x;  // 0..65535
  const int d = gid >> 6;
  const int e = gid & 63;
  ptt[gid] = proto[(size_t)e * DD + d];
}

// ---- K1: normalized per-row dots ------------------------------------------
__global__ __launch_bounds__(256, 2) void router_dots(
    const float* __restrict__ x, const float* __restrict__ ptt,
    float* __restrict__ dots) {
  __shared__ float xt[4][2][16][36];  // per-wave double-buffered x chunk
  __shared__ float B0[32][68];        // reduction buffers
  __shared__ float B1[32][68];
  __shared__ float nq[4][32];         // per-wave per-token sumsq partials

  const int lane = threadIdx.x & 63;
  const int w    = __builtin_amdgcn_readfirstlane(threadIdx.x >> 6);
  const int b    = blockIdx.x >> 6;          // 64 blocks per batch
  const int s0   = (blockIdx.x & 63) * 32;   // 32 tokens per block

  const int toks = lane & 31;  // staging: token
  const int kh   = lane >> 5;  // staging: k-half (8 floats)
  const int eg   = lane & 7;   // tile: expert group (8 e)
  const int tg   = lane >> 3;  // tile: token group (4 t)

  const float* xb = x + ((size_t)b * SS + s0) * DD;
  const int kbase = w * 256;   // this wave's k-slice

  float4 acc0[4], acc1[4];
#pragma unroll
  for (int i = 0; i < 4; ++i) {
    acc0[i] = make_float4(0.f, 0.f, 0.f, 0.f);
    acc1[i] = make_float4(0.f, 0.f, 0.f, 0.f);
  }
  float q = 0.0f;

  // ---- preload + stage chunk 0 into buf 0 ----
  {
    const float* xs = xb + (size_t)toks * DD + kbase + kh * 8;
    const float4 va = *(const float4*)(xs);
    const float4 vb = *(const float4*)(xs + 4);
    q += SUMSQ4(va) + SUMSQ4(vb);
    float* dstc = &xt[w][0][0][toks];
    dstc[(kh * 8 + 0) * 36] = va.x;
    dstc[(kh * 8 + 1) * 36] = va.y;
    dstc[(kh * 8 + 2) * 36] = va.z;
    dstc[(kh * 8 + 3) * 36] = va.w;
    dstc[(kh * 8 + 4) * 36] = vb.x;
    dstc[(kh * 8 + 5) * 36] = vb.y;
    dstc[(kh * 8 + 6) * 36] = vb.z;
    dstc[(kh * 8 + 7) * 36] = vb.w;
  }

  // ---- proto rotation preload: k = kbase..kbase+3 ----
  float4 pp0[4], pp1[4];
#pragma unroll
  for (int r = 0; r < 4; ++r) {
    const float* pr = ptt + (size_t)(kbase + r) * EE + eg * 8;
    pp0[r] = *(const float4*)(pr);
    pp1[r] = *(const float4*)(pr + 4);
  }

  for (int c = 0; c < 16; ++c) {   // 16 chunks x 16 k = 256 k
    const int cur = c & 1;
    // ---- prefetch next chunk's x (consumed after the k-loop) ----
    float4 na, nb;
    if (c + 1 < 16) {
      const float* xs = xb + (size_t)toks * DD + kbase + (c + 1) * 16 + kh * 8;
      na = *(const float4*)(xs);
      nb = *(const float4*)(xs + 4);
    }
    // ---- 16 k-steps: ds_read x-frag + rotated proto + 32 fmac ----
#pragma unroll
    for (int kk = 0; kk < 16; ++kk) {
      const int slot = kk & 3;
      const float4 xf = *(const float4*)(&xt[w][cur][kk][tg * 4]);
      const float4 p0 = pp0[slot];
      const float4 p1 = pp1[slot];
      int kpre = kbase + c * 16 + kk + 4;            // continuous rotation
      if (kpre > kbase + 255) kpre = kbase + 255;    // slice-tail clamp
      const float* pr = ptt + (size_t)kpre * EE + eg * 8;
      pp0[slot] = *(const float4*)(pr);
      pp1[slot] = *(const float4*)(pr + 4);
      FMA4(acc0[0], xf.x, p0) FMA4(acc1[0], xf.x, p1)
      FMA4(acc0[1], xf.y, p0) FMA4(acc1[1], xf.y, p1)
      FMA4(acc0[2], xf.z, p0) FMA4(acc1[2], xf.z, p1)
      FMA4(acc0[3], xf.w, p0) FMA4(acc1[3], xf.w, p1)
    }
    // ---- stage prefetched chunk into the other buffer ----
    if (c + 1 < 16) {
      q += SUMSQ4(na) + SUMSQ4(nb);
      float* dstc = &xt[w][cur ^ 1][0][toks];
      dstc[(kh * 8 + 0) * 36] = na.x;
      dstc[(kh * 8 + 1) * 36] = na.y;
      dstc[(kh * 8 + 2) * 36] = na.z;
      dstc[(kh * 8 + 3) * 36] = na.w;
      dstc[(kh * 8 + 4) * 36] = nb.x;
      dstc[(kh * 8 + 5) * 36] = nb.y;
      dstc[(kh * 8 + 6) * 36] = nb.z;
      dstc[(kh * 8 + 7) * 36] = nb.w;
    }
  }

  // sumsq: combine the two k-halves of each token; kh==0 lanes publish
  q += __shfl_xor(q, 32);
  if (kh == 0) nq[w][toks] = q;

#define WRB(R)                                                  \
  { _Pragma("unroll") for (int i = 0; i < 4; ++i) {             \
      *(float4*)(&(R)[tg * 4 + i][eg * 8])     = acc0[i];       \
      *(float4*)(&(R)[tg * 4 + i][eg * 8 + 4]) = acc1[i]; } }
#define ADDB(R)                                                 \
  { _Pragma("unroll") for (int i = 0; i < 4; ++i) {             \
      const float4 t0 = *(const float4*)(&(R)[tg * 4 + i][eg * 8]);     \
      const float4 t1 = *(const float4*)(&(R)[tg * 4 + i][eg * 8 + 4]); \
      acc0[i].x += t0.x; acc0[i].y += t0.y;                     \
      acc0[i].z += t0.z; acc0[i].w += t0.w;                     \
      acc1[i].x += t1.x; acc1[i].y += t1.y;                     \
      acc1[i].z += t1.z; acc1[i].w += t1.w; } }

  // deterministic tree: ((w0+w1) + (w2+w3))
  __syncthreads();
  if (w == 1) WRB(B0)
  if (w == 3) WRB(B1)
  __syncthreads();
  if (w == 0) ADDB(B0)
  if (w == 2) ADDB(B1)
  __syncthreads();
  if (w == 2) WRB(B0)
  __syncthreads();
  if (w == 0) {
    ADDB(B0)
#pragma unroll
    for (int i = 0; i < 4; ++i) {
      const int row = tg * 4 + i;
      const float qs = nq[0][row] + nq[1][row] + nq[2][row] + nq[3][row];
      const float inv = 1.0f / fmaxf(sqrtf(qs), EPSV);
      float4 o0, o1;
      o0.x = acc0[i].x * inv; o0.y = acc0[i].y * inv;
      o0.z = acc0[i].z * inv; o0.w = acc0[i].w * inv;
      o1.x = acc1[i].x * inv; o1.y = acc1[i].y * inv;
      o1.z = acc1[i].z * inv; o1.w = acc1[i].w * inv;
      float* dp = dots + ((size_t)b * SS + s0 + row) * EE + eg * 8;
      *(float4*)(dp)     = o0;
      *(float4*)(dp + 4) = o1;
    }
  }
}

// ---- K2: window-3 + top-2 + renorm softmax (array-free, R7-verified) -------
#define T2UP(s, ei)                                            \
  if ((s) > v1) { v2 = v1; i2 = i1; v1 = (s); i1 = (ei); }     \
  else if ((s) > v2) { v2 = (s); i2 = (ei); }

__global__ __launch_bounds__(256) void router_top2(
    const float* __restrict__ dots, float* __restrict__ out) {
  const int gtid = blockIdx.x * 256 + threadIdx.x;  // 0..32767
  const int tok  = gtid >> 1;          // global token
  const int h    = gtid & 1;           // expert half (32 each)
  const int b    = tok >> 11;
  const int sl   = tok & (SS - 1);
  const int r0   = (sl >= 2) ? sl - 2 : 0;   // causal pad: replicate token 0
  const int r1   = (sl >= 1) ? sl - 1 : 0;

  const float* d0 = dots + ((size_t)b * SS + r0) * EE + h * 32;
  const float* d1 = dots + ((size_t)b * SS + r1) * EE + h * 32;
  const float* d2 = dots + ((size_t)b * SS + sl) * EE + h * 32;

  float v1 = -INFINITY, v2 = -INFINITY;
  int i1 = 0, i2 = 0;
#pragma unroll
  for (int qd = 0; qd < 8; ++qd) {
    const float4 a = *(const float4*)(d0 + qd * 4);
    const float4 c = *(const float4*)(d1 + qd * 4);
    const float4 e = *(const float4*)(d2 + qd * 4);
    const int e0 = h * 32 + qd * 4;
    float s;
    s = a.x + c.x + e.x; T2UP(s, e0 + 0)
    s = a.y + c.y + e.y; T2UP(s, e0 + 1)
    s = a.z + c.z + e.z; T2UP(s, e0 + 2)
    s = a.w + c.w + e.w; T2UP(s, e0 + 3)
  }

  {  // merge the two halves (partner lane = lane^1); tie -> lower index
    const float ov1 = __shfl_xor(v1, 1);
    const int   oi1 = __shfl_xor(i1, 1);
    const float ov2 = __shfl_xor(v2, 1);
    const int   oi2 = __shfl_xor(i2, 1);
    const bool o_beats = (ov1 > v1) || (ov1 == v1 && oi1 < i1);
    if (o_beats) {
      const bool v1_beats_o2 = (v1 > ov2) || (v1 == ov2 && i1 < oi2);
      v2 = v1_beats_o2 ? v1 : ov2;
      i2 = v1_beats_o2 ? i1 : oi2;
      v1 = ov1;
      i1 = oi1;
    } else {
      const bool o1_beats_v2 = (ov1 > v2) || (ov1 == v2 && oi1 < i2);
      if (o1_beats_v2) { v2 = ov1; i2 = oi1; }
    }
  }

  if (h == 0) {
    const float ex = expf((v2 - v1) * (1.0f / 3.0f));  // <= 1
    const float w1 = 1.0f / (1.0f + ex);
    const size_t o = (size_t)tok * 2;
    *(float2*)(out + o) = make_float2((float)i1, (float)i2);
    *(float2*)(out + (size_t)BB * SS * 2 + o) = make_float2(w1, ex * w1);
  }
}

extern "C" void kernel_launch(void* const* d_in, const int* in_sizes, int n_in,
                              void* d_out, int out_size, void* d_ws, size_t ws_size,
                              hipStream_t stream) {
  const float* x     = (const float*)d_in[0];
  const float* proto = (const float*)d_in[1];
  // d_in[2] = attn_mask: unused by the reference output path.
  float* out  = (float*)d_out;
  float* ptt  = (float*)d_ws;                          // 256 KiB ptt[d][e]
  float* dots = (float*)((char*)d_ws + (512 << 10));   // 4 MiB normalized dots

  repack_proto<<<dim3(256), dim3(256), 0, stream>>>(proto, ptt);
  router_dots<<<dim3(512), dim3(256), 0, stream>>>(x, ptt, dots);
  router_top2<<<dim3(128), dim3(256), 0, stream>>>(dots, out);
}